// Round 8
// baseline (2171.321 us; speedup 1.0000x reference)
//
#include <hip/hip_runtime.h>
#include <math.h>

typedef __bf16 bf16x8 __attribute__((ext_vector_type(8)));
typedef float f32x4 __attribute__((ext_vector_type(4)));
typedef unsigned long long u64;

#define HD 512
#define NB 128
#define NI 32
#define NL 96
#define NS 16
#define NF 24
#define NSTEP 23
#define TS2 72   // padded LDS transpose stride (shorts) for 64-wide tiles

#define MFMA16(a,b,c) __builtin_amdgcn_mfma_f32_16x16x32_bf16(a,b,c,0,0,0)

__device__ __forceinline__ unsigned short f2bf(float f) {
    union { float f; unsigned u; } v; v.f = f;
    unsigned r = v.u + 0x7fffu + ((v.u >> 16) & 1u);
    return (unsigned short)(r >> 16);
}
__device__ __forceinline__ float bf2f(unsigned short h) {
    union { unsigned u; float f; } v; v.u = ((unsigned)h) << 16;
    return v.f;
}
__device__ __forceinline__ void split_bf(float v, unsigned short& hi, unsigned short& lo) {
    unsigned short h = f2bf(v);
    hi = h;
    lo = f2bf(v - bf2f(h));
}
__device__ __forceinline__ float sigm(float x) { return 1.0f / (1.0f + __expf(-x)); }
__device__ __forceinline__ float softp(float x) {
    return fmaxf(x, 0.0f) + log1pf(__expf(-fabsf(x)));
}
__device__ __forceinline__ bf16x8 ld8(const unsigned short* p) {
    return *reinterpret_cast<const bf16x8*>(p);
}
__device__ __forceinline__ f32x4 mfma3(bf16x8 ahi, bf16x8 alo, const unsigned short* bp, f32x4 c) {
    bf16x8 bhi = ld8(bp);
    bf16x8 blo = ld8(bp + 8);
    c = MFMA16(ahi, bhi, c);
    c = MFMA16(alo, bhi, c);
    c = MFMA16(ahi, blo, c);
    return c;
}

// ---- device-coherent state exchange: relaxed agent-scope 8B atomics, SoA tiles ----
__device__ __forceinline__ void st_frag(u64* tile, int lane, bf16x8 hi, bf16x8 lo) {
    union { bf16x8 v; u64 q[2]; } h, l;
    h.v = hi; l.v = lo;
    __hip_atomic_store(tile + 0 * 64 + lane, h.q[0], __ATOMIC_RELAXED, __HIP_MEMORY_SCOPE_AGENT);
    __hip_atomic_store(tile + 1 * 64 + lane, h.q[1], __ATOMIC_RELAXED, __HIP_MEMORY_SCOPE_AGENT);
    __hip_atomic_store(tile + 2 * 64 + lane, l.q[0], __ATOMIC_RELAXED, __HIP_MEMORY_SCOPE_AGENT);
    __hip_atomic_store(tile + 3 * 64 + lane, l.q[1], __ATOMIC_RELAXED, __HIP_MEMORY_SCOPE_AGENT);
}
__device__ __forceinline__ void ld_frag(const u64* tile, int lane, bf16x8& hi, bf16x8& lo) {
    union { bf16x8 v; u64 q[2]; } h, l;
    h.q[0] = __hip_atomic_load(tile + 0 * 64 + lane, __ATOMIC_RELAXED, __HIP_MEMORY_SCOPE_AGENT);
    h.q[1] = __hip_atomic_load(tile + 1 * 64 + lane, __ATOMIC_RELAXED, __HIP_MEMORY_SCOPE_AGENT);
    l.q[0] = __hip_atomic_load(tile + 2 * 64 + lane, __ATOMIC_RELAXED, __HIP_MEMORY_SCOPE_AGENT);
    l.q[1] = __hip_atomic_load(tile + 3 * 64 + lane, __ATOMIC_RELAXED, __HIP_MEMORY_SCOPE_AGENT);
    hi = h.v; lo = l.v;
}
// barrier: drain own vmem, block-barrier, relaxed counter, spin. No __threadfence.
__device__ __forceinline__ void gbar(unsigned* ctr, unsigned target) {
    __builtin_amdgcn_s_waitcnt(0);
    __syncthreads();
    if (threadIdx.x == 0) {
        __hip_atomic_fetch_add(ctr, 1u, __ATOMIC_RELAXED, __HIP_MEMORY_SCOPE_AGENT);
        while (__hip_atomic_load(ctr, __ATOMIC_RELAXED, __HIP_MEMORY_SCOPE_AGENT) < target)
            __builtin_amdgcn_s_sleep(2);
    }
    __syncthreads();
}

// ---------- prep: pack W[N][K] fp32 -> split bf16 B-fragments ----------
__global__ void pack_w(const float* __restrict__ W, unsigned short* __restrict__ Wp,
                       int N, int K) {
    int idx = blockIdx.x * 256 + threadIdx.x;
    int total = (N / 16) * (K / 32) * 64;
    if (idx >= total) return;
    int lane = idx & 63;
    int t2 = idx >> 6;
    int KT = K / 32;
    int kt = t2 % KT, nt = t2 / KT;
    const float* src = W + (size_t)(nt * 16 + (lane & 15)) * K + kt * 32 + (lane >> 4) * 8;
    unsigned short* dst = Wp + (size_t)idx * 16;
    #pragma unroll
    for (int j = 0; j < 8; ++j) split_bf(src[j], dst[j], dst[8 + j]);
}

// ---------- prep: x[B][I][L] fp32 -> xhi/xlo [L][B][I] bf16 ----------
__global__ void pack_x(const float* __restrict__ x, unsigned short* __restrict__ xhi,
                       unsigned short* __restrict__ xlo) {
    int idx = blockIdx.x * 256 + threadIdx.x;
    if (idx >= NL * NB) return;
    int b = idx % NB, l = idx / NB;
    size_t base = (size_t)(l * NB + b) * NI;
    #pragma unroll
    for (int i = 0; i < NI; ++i)
        split_bf(x[((size_t)b * NI + i) * NL + l], xhi[base + i], xlo[base + i]);
}

// =================== fused cooperative kernel ===================
__global__ __launch_bounds__(512) void coop_all(
    const unsigned short* __restrict__ xhi, const unsigned short* __restrict__ xlo,
    const unsigned short* __restrict__ wih_p, const unsigned short* __restrict__ whh_p,
    const unsigned short* __restrict__ w1_p, const unsigned short* __restrict__ w2_p,
    const unsigned short* __restrict__ gw_p, const unsigned short* __restrict__ dwhh_p,
    const unsigned short* __restrict__ outw_p,
    const float* __restrict__ ebih, const float* __restrict__ ebhh,
    const float* __restrict__ fb1, const float* __restrict__ fb2,
    const float* __restrict__ gb, const float* __restrict__ dbih,
    const float* __restrict__ dbhh, const float* __restrict__ outb,
    const float* __restrict__ noise,
    u64* hE0, u64* hE1, u64* hP0, u64* hP1, u64* uP,
    unsigned* h_encF, float* out, unsigned* bar)
{
    const int bid = blockIdx.x;
    const int tid = threadIdx.x, lane = tid & 63, wv = tid >> 6;
    const int l15 = lane & 15, g4 = lane >> 4;
    const f32x4 zz = {0.f, 0.f, 0.f, 0.f};

    __shared__ float pred[4][8][16][16];
    __shared__ __align__(16) unsigned short Thi[64][TS2];
    __shared__ __align__(16) unsigned short Tlo[64][TS2];

    // =============== encoder: group g = m-tile (16 rows), slice n = 16 units ===============
    {
        const int g = bid & 7, n = bid >> 3;
        unsigned* ctr = bar + (1 + g) * 16;
        float hcell = 0.f;
        float cr = 0.f, cz = 0.f, binx = 0.f, bhnn = 0.f;
        const int crow = tid >> 4, cunit = tid & 15;
        if (tid < 256) {
            int u = n * 16 + cunit;
            cr = ebih[u] + ebhh[u];
            cz = ebih[HD + u] + ebhh[HD + u];
            binx = ebih[2 * HD + u];
            bhnn = ebhh[2 * HD + u];
        }
        u64* hEbuf[2] = {hE0, hE1};
        #pragma unroll 1
        for (int l = 0; l < NL; ++l) {
            const u64* cur = hEbuf[l & 1];
            u64* nxt = hEbuf[(l & 1) ^ 1];
            f32x4 pr = zz, pz = zz, pnh = zz, pnx = zz;
            if (wv == 0) {
                size_t xb = (size_t)(l * NB + g * 16 + l15) * NI + g4 * 8;
                bf16x8 axh = ld8(xhi + xb), axl = ld8(xlo + xb);
                pr  = mfma3(axh, axl, wih_p + ((size_t)(0 * 32 + n) * 64 + lane) * 16, pr);
                pz  = mfma3(axh, axl, wih_p + ((size_t)(1 * 32 + n) * 64 + lane) * 16, pz);
                pnx = mfma3(axh, axl, wih_p + ((size_t)(2 * 32 + n) * 64 + lane) * 16, pnx);
            }
            #pragma unroll
            for (int kk = 0; kk < 2; ++kk) {
                int kt = wv * 2 + kk;
                bf16x8 ah, al;
                ld_frag(cur + (size_t)(g * 16 + kt) * 256, lane, ah, al);
                pr  = mfma3(ah, al, whh_p + ((size_t)((0 * 32 + n) * 16 + kt) * 64 + lane) * 16, pr);
                pz  = mfma3(ah, al, whh_p + ((size_t)((1 * 32 + n) * 16 + kt) * 64 + lane) * 16, pz);
                pnh = mfma3(ah, al, whh_p + ((size_t)((2 * 32 + n) * 16 + kt) * 64 + lane) * 16, pnh);
            }
            #pragma unroll
            for (int v = 0; v < 4; ++v) {
                pred[0][wv][g4 * 4 + v][l15] = pr[v];
                pred[1][wv][g4 * 4 + v][l15] = pz[v];
                pred[2][wv][g4 * 4 + v][l15] = pnh[v];
                if (wv == 0) pred[3][0][g4 * 4 + v][l15] = pnx[v];
            }
            __syncthreads();
            if (tid < 256) {
                float ar = 0.f, az = 0.f, anh_ = 0.f;
                #pragma unroll
                for (int w = 0; w < 8; ++w) {
                    ar += pred[0][w][crow][cunit];
                    az += pred[1][w][crow][cunit];
                    anh_ += pred[2][w][crow][cunit];
                }
                float anx_ = pred[3][0][crow][cunit];
                float r = sigm(ar + cr);
                float z = sigm(az + cz);
                float nn = tanhf(anx_ + binx + r * (anh_ + bhnn));
                hcell = (1.f - z) * nn + z * hcell;
                unsigned short hi, lo;
                split_bf(hcell, hi, lo);
                Thi[crow][cunit] = hi;
                Tlo[crow][cunit] = lo;
                if (l == NL - 1)
                    __hip_atomic_store(h_encF + (size_t)(g * 16 + crow) * HD + n * 16 + cunit,
                                       __float_as_uint(hcell),
                                       __ATOMIC_RELAXED, __HIP_MEMORY_SCOPE_AGENT);
            }
            __syncthreads();
            if (tid < 32) {
                int half = n & 1, kt = n >> 1;
                int lp = half * 32 + tid;
                bf16x8 vh = *(const bf16x8*)&Thi[tid & 15][(tid >> 4) * 8];
                bf16x8 vl = *(const bf16x8*)&Tlo[tid & 15][(tid >> 4) * 8];
                st_frag(nxt + (size_t)(g * 16 + kt) * 256, lp, vh, vl);
            }
            gbar(ctr, 32u * (l + 1));
        }
    }

    // full-grid barrier: h_encF + final frags (hE0) visible
    gbar(bar, 256u);

    // ====== SDE + decoder: 32 groups x 8 blocks; group = 64 rows, slice = 64 units ======
    const int g2 = (bid & 7) * 4 + ((bid >> 3) & 3);   // XCD-local groups
    const int n2 = bid >> 5;                           // 0..7: 64-unit slice
    unsigned* ctr2 = bar + (9 + g2) * 16;
    const int mt = wv & 3, nh = wv >> 2;               // wave = (m-tile, n-half)
    const int smp = g2 >> 1;                           // sample index
    const int b0 = (g2 & 1) * 64 + mt * 16;            // batch row base for this wave
    const float dt = (float)NF / (float)NSTEP;
    const float sqdt = sqrtf(dt);

    float hreg[2][4];
    #pragma unroll
    for (int nt = 0; nt < 2; ++nt)
        #pragma unroll
        for (int v = 0; v < 4; ++v)
            hreg[nt][v] = __uint_as_float(__hip_atomic_load(
                h_encF + (size_t)(b0 + g4 * 4 + v) * HD + n2 * 64 + nh * 32 + nt * 16 + l15,
                __ATOMIC_RELAXED, __HIP_MEMORY_SCOPE_AGENT));

    float b1v[2], b2v[2], gbv[2];
    #pragma unroll
    for (int nt = 0; nt < 2; ++nt) {
        int u = n2 * 64 + nh * 32 + nt * 16 + l15;
        b1v[nt] = fb1[u]; b2v[nt] = fb2[u]; gbv[nt] = gb[u];
    }

    u64* hPb[2] = {hP0, hP1};
    int cur = 0;
    const int tmt = (tid >> 6) & 3, ko = tid >> 8, ln = tid & 63;  // transpose-write roles

    #pragma unroll 1
    for (int st = 0; st < NSTEP; ++st) {
        const u64* hsrc = (st == 0) ? hE0 : hPb[cur];
        const int tb = (st == 0) ? ((g2 & 1) * 4 + mt) : (g2 * 4 + mt);
        // ---- phase A: u = tanh(h W1^T + b1)  AND  g-pre = h gW^T ----
        f32x4 au[2] = {zz, zz}, ag[2] = {zz, zz};
        #pragma unroll 4
        for (int kt = 0; kt < 16; ++kt) {
            bf16x8 ah, al;
            ld_frag(hsrc + (size_t)(tb * 16 + kt) * 256, lane, ah, al);
            #pragma unroll
            for (int nt = 0; nt < 2; ++nt) {
                int nn = n2 * 4 + nh * 2 + nt;
                au[nt] = mfma3(ah, al, w1_p + ((size_t)(nn * 16 + kt) * 64 + lane) * 16, au[nt]);
                ag[nt] = mfma3(ah, al, gw_p + ((size_t)(nn * 16 + kt) * 64 + lane) * 16, ag[nt]);
            }
        }
        #pragma unroll
        for (int nt = 0; nt < 2; ++nt)
            #pragma unroll
            for (int v = 0; v < 4; ++v) {
                unsigned short hi, lo;
                split_bf(tanhf(au[nt][v] + b1v[nt]), hi, lo);
                Thi[mt * 16 + g4 * 4 + v][nh * 32 + nt * 16 + l15] = hi;
                Tlo[mt * 16 + g4 * 4 + v][nh * 32 + nt * 16 + l15] = lo;
            }
        __syncthreads();
        {
            bf16x8 vh = *(const bf16x8*)&Thi[tmt * 16 + (ln & 15)][ko * 32 + (ln >> 4) * 8];
            bf16x8 vl = *(const bf16x8*)&Tlo[tmt * 16 + (ln & 15)][ko * 32 + (ln >> 4) * 8];
            st_frag(uP + (size_t)((g2 * 4 + tmt) * 16 + n2 * 2 + ko) * 256, ln, vh, vl);
        }
        gbar(ctr2, 8u * (2 * st + 1));
        // ---- phase B: f = u W2^T + b2 ----
        f32x4 af[2] = {zz, zz};
        #pragma unroll 4
        for (int kt = 0; kt < 16; ++kt) {
            bf16x8 uh, ul;
            ld_frag(uP + (size_t)((g2 * 4 + mt) * 16 + kt) * 256, lane, uh, ul);
            #pragma unroll
            for (int nt = 0; nt < 2; ++nt) {
                int nn = n2 * 4 + nh * 2 + nt;
                af[nt] = mfma3(uh, ul, w2_p + ((size_t)(nn * 16 + kt) * 64 + lane) * 16, af[nt]);
            }
        }
        #pragma unroll
        for (int nt = 0; nt < 2; ++nt)
            #pragma unroll
            for (int v = 0; v < 4; ++v) {
                int b = b0 + g4 * 4 + v;
                size_t nidx = ((size_t)(smp * NSTEP + st) * NB + b) * HD
                              + n2 * 64 + nh * 32 + nt * 16 + l15;
                float nz = noise[nidx];
                float f = af[nt][v] + b2v[nt];
                float gg = softp(ag[nt][v] + gbv[nt]);
                hreg[nt][v] += f * dt + gg * sqdt * nz;
                unsigned short hi, lo;
                split_bf(hreg[nt][v], hi, lo);
                Thi[mt * 16 + g4 * 4 + v][nh * 32 + nt * 16 + l15] = hi;
                Tlo[mt * 16 + g4 * 4 + v][nh * 32 + nt * 16 + l15] = lo;
            }
        __syncthreads();
        {
            bf16x8 vh = *(const bf16x8*)&Thi[tmt * 16 + (ln & 15)][ko * 32 + (ln >> 4) * 8];
            bf16x8 vl = *(const bf16x8*)&Tlo[tmt * 16 + (ln & 15)][ko * 32 + (ln >> 4) * 8];
            st_frag(hPb[cur ^ 1] + (size_t)((g2 * 4 + tmt) * 16 + n2 * 2 + ko) * 256, ln, vh, vl);
        }
        cur ^= 1;
        gbar(ctr2, 8u * (2 * st + 2));
    }

    // =============== decoder GRU + out-proj ===============
    float crv[2], czv[2], binv[2], bhnv[2], obias[2];
    #pragma unroll
    for (int nt = 0; nt < 2; ++nt) {
        int u = n2 * 64 + nh * 32 + nt * 16 + l15;
        crv[nt] = dbih[u] + dbhh[u];
        czv[nt] = dbih[HD + u] + dbhh[HD + u];
        binv[nt] = dbih[2 * HD + u];
        bhnv[nt] = dbhh[2 * HD + u];
        obias[nt] = (n2 == 0 && nh == 0) ? outb[nt * 16 + l15] : 0.f;
    }
    const bool owave = (n2 == 0 && nh == 0);

    #pragma unroll 1
    for (int j = 0; j < NF; ++j) {
        const u64* hsrc = hPb[cur];
        f32x4 ar[2] = {zz, zz}, az2[2] = {zz, zz}, anh[2] = {zz, zz};
        f32x4 ao[2] = {zz, zz};
        #pragma unroll 4
        for (int kt = 0; kt < 16; ++kt) {
            bf16x8 ah, al;
            ld_frag(hsrc + (size_t)((g2 * 4 + mt) * 16 + kt) * 256, lane, ah, al);
            #pragma unroll
            for (int nt = 0; nt < 2; ++nt) {
                int nn = n2 * 4 + nh * 2 + nt;
                ar[nt]  = mfma3(ah, al, dwhh_p + ((size_t)((0 * 32 + nn) * 16 + kt) * 64 + lane) * 16, ar[nt]);
                az2[nt] = mfma3(ah, al, dwhh_p + ((size_t)((1 * 32 + nn) * 16 + kt) * 64 + lane) * 16, az2[nt]);
                anh[nt] = mfma3(ah, al, dwhh_p + ((size_t)((2 * 32 + nn) * 16 + kt) * 64 + lane) * 16, anh[nt]);
            }
            if (owave && j >= 1) {
                #pragma unroll
                for (int nt = 0; nt < 2; ++nt)
                    ao[nt] = mfma3(ah, al, outw_p + ((size_t)(nt * 16 + kt) * 64 + lane) * 16, ao[nt]);
            }
        }
        if (owave && j >= 1) {
            #pragma unroll
            for (int nt = 0; nt < 2; ++nt)
                #pragma unroll
                for (int v = 0; v < 4; ++v) {
                    int b = b0 + g4 * 4 + v;
                    out[(((size_t)smp * NB + b) * NI + nt * 16 + l15) * NF + (j - 1)] = ao[nt][v] + obias[nt];
                }
        }
        #pragma unroll
        for (int nt = 0; nt < 2; ++nt)
            #pragma unroll
            for (int v = 0; v < 4; ++v) {
                float r = sigm(ar[nt][v] + crv[nt]);
                float z = sigm(az2[nt][v] + czv[nt]);
                float nn2 = tanhf(binv[nt] + r * (anh[nt][v] + bhnv[nt]));
                hreg[nt][v] = (1.f - z) * nn2 + z * hreg[nt][v];
                unsigned short hi, lo;
                split_bf(hreg[nt][v], hi, lo);
                Thi[mt * 16 + g4 * 4 + v][nh * 32 + nt * 16 + l15] = hi;
                Tlo[mt * 16 + g4 * 4 + v][nh * 32 + nt * 16 + l15] = lo;
            }
        __syncthreads();
        {
            bf16x8 vh = *(const bf16x8*)&Thi[tmt * 16 + (ln & 15)][ko * 32 + (ln >> 4) * 8];
            bf16x8 vl = *(const bf16x8*)&Tlo[tmt * 16 + (ln & 15)][ko * 32 + (ln >> 4) * 8];
            st_frag(hPb[cur ^ 1] + (size_t)((g2 * 4 + tmt) * 16 + n2 * 2 + ko) * 256, ln, vh, vl);
        }
        cur ^= 1;
        gbar(ctr2, 8u * (2 * NSTEP + j + 1));
    }
    // epilogue: final output column (j = NF) — out-proj waves only, no barrier needed
    if (owave) {
        f32x4 ao[2] = {zz, zz};
        #pragma unroll 4
        for (int kt = 0; kt < 16; ++kt) {
            bf16x8 ah, al;
            ld_frag(hPb[cur] + (size_t)((g2 * 4 + mt) * 16 + kt) * 256, lane, ah, al);
            #pragma unroll
            for (int nt = 0; nt < 2; ++nt)
                ao[nt] = mfma3(ah, al, outw_p + ((size_t)(nt * 16 + kt) * 64 + lane) * 16, ao[nt]);
        }
        #pragma unroll
        for (int nt = 0; nt < 2; ++nt)
            #pragma unroll
            for (int v = 0; v < 4; ++v) {
                int b = b0 + g4 * 4 + v;
                out[(((size_t)smp * NB + b) * NI + nt * 16 + l15) * NF + (NF - 1)] = ao[nt][v] + obias[nt];
            }
    }
}

extern "C" void kernel_launch(void* const* d_in, const int* in_sizes, int n_in,
                              void* d_out, int out_size, void* d_ws, size_t ws_size,
                              hipStream_t stream) {
    const float* x       = (const float*)d_in[0];
    const float* noise   = (const float*)d_in[1];
    const float* enc_Wih = (const float*)d_in[2];
    const float* enc_Whh = (const float*)d_in[3];
    const float* enc_bih = (const float*)d_in[4];
    const float* enc_bhh = (const float*)d_in[5];
    const float* f_W1    = (const float*)d_in[6];
    const float* f_b1    = (const float*)d_in[7];
    const float* f_W2    = (const float*)d_in[8];
    const float* f_b2    = (const float*)d_in[9];
    const float* g_W     = (const float*)d_in[10];
    const float* g_b     = (const float*)d_in[11];
    const float* dec_Whh = (const float*)d_in[13];
    const float* dec_bih = (const float*)d_in[14];
    const float* dec_bhh = (const float*)d_in[15];
    const float* out_W   = (const float*)d_in[16];
    const float* out_b   = (const float*)d_in[17];
    float* out = (float*)d_out;

    char* ws = (char*)d_ws;
    unsigned short* whh_p  = (unsigned short*)(ws + 0);          // 3 MB
    unsigned short* wih_p  = (unsigned short*)(ws + 3145728);    // 192 KB
    unsigned short* w1_p   = (unsigned short*)(ws + 3342336);    // 1 MB
    unsigned short* w2_p   = (unsigned short*)(ws + 4390912);    // 1 MB
    unsigned short* gw_p   = (unsigned short*)(ws + 5439488);    // 1 MB
    unsigned short* dwhh_p = (unsigned short*)(ws + 6488064);    // 3 MB
    unsigned short* outw_p = (unsigned short*)(ws + 9633792);    // 64 KB
    unsigned short* xhi    = (unsigned short*)(ws + 9699328);    // 768 KB
    unsigned short* xlo    = (unsigned short*)(ws + 10485760);   // 768 KB
    u64*            hE1    = (u64*)(ws + 11272192);              // 256 KB
    u64*            hP0    = (u64*)(ws + 11534336);              // 4 MB
    u64*            hP1    = (u64*)(ws + 15728640);              // 4 MB
    u64*            uP     = (u64*)(ws + 19922944);              // 4 MB
    unsigned*       h_encF = (unsigned*)(ws + 24117248);         // 256 KB
    unsigned*       bar    = (unsigned*)(ws + 24379392);         // 4 KB
    u64*            hE0    = (u64*)(ws + 24383488);              // 256 KB (contiguous w/ bar)

    // zero barrier counters + initial encoder h fragments
    hipMemsetAsync(ws + 24379392, 0, 4096 + 262144, stream);

    pack_w<<<384, 256, 0, stream>>>(enc_Whh, whh_p, 3 * HD, HD);
    pack_w<<<24, 256, 0, stream>>>(enc_Wih, wih_p, 3 * HD, NI);
    pack_w<<<128, 256, 0, stream>>>(f_W1, w1_p, HD, HD);
    pack_w<<<128, 256, 0, stream>>>(f_W2, w2_p, HD, HD);
    pack_w<<<128, 256, 0, stream>>>(g_W, gw_p, HD, HD);
    pack_w<<<384, 256, 0, stream>>>(dec_Whh, dwhh_p, 3 * HD, HD);
    pack_w<<<8, 256, 0, stream>>>(out_W, outw_p, NI, HD);
    pack_x<<<48, 256, 0, stream>>>(x, xhi, xlo);

    void* args[] = {
        (void*)&xhi, (void*)&xlo, (void*)&wih_p, (void*)&whh_p,
        (void*)&w1_p, (void*)&w2_p, (void*)&gw_p, (void*)&dwhh_p, (void*)&outw_p,
        (void*)&enc_bih, (void*)&enc_bhh, (void*)&f_b1, (void*)&f_b2,
        (void*)&g_b, (void*)&dec_bih, (void*)&dec_bhh, (void*)&out_b,
        (void*)&noise,
        (void*)&hE0, (void*)&hE1, (void*)&hP0, (void*)&hP1, (void*)&uP,
        (void*)&h_encF, (void*)&out, (void*)&bar
    };
    hipLaunchCooperativeKernel((void*)coop_all, dim3(256), dim3(512), args, 0, stream);
}